// Round 7
// baseline (523.446 us; speedup 1.0000x reference)
//
#include <hip/hip_runtime.h>

#define DEV __device__ __forceinline__

typedef __attribute__((ext_vector_type(8))) short bf16x8;
typedef __attribute__((ext_vector_type(4))) float f32x4;

constexpr int D_MODEL = 2048;
constexpr int NHEAD = 16;
constexpr int DH = 128;
constexpr int SS = 2048;   // sequence length
constexpr int KK = 2048;   // GEMM K dim

DEV unsigned short f2bf(float f) {
  unsigned int u = __builtin_bit_cast(unsigned int, f);
  u = (u + 0x7fff + ((u >> 16) & 1)) >> 16;  // RNE
  return (unsigned short)u;
}

DEV void async16(const void* g, void* l) {
  __builtin_amdgcn_global_load_lds(
      (const __attribute__((address_space(1))) unsigned int*)g,
      (__attribute__((address_space(3))) unsigned int*)l, 16, 0, 0);
}

DEV f32x4 mfma16(bf16x8 a, bf16x8 b, f32x4 c) {
  return __builtin_amdgcn_mfma_f32_16x16x32_bf16(a, b, c, 0, 0, 0);
}

// ---------------- cast fp32 -> bf16: x (8.4M) + wq,wk,wv,wo (4x4.19M) ----------
__global__ __launch_bounds__(256) void cast_all(
    const float* __restrict__ x, const float* __restrict__ wq,
    const float* __restrict__ wk, const float* __restrict__ wv,
    const float* __restrict__ wo, unsigned short* __restrict__ xb,
    unsigned short* __restrict__ wb) {
  long i4 = ((long)blockIdx.x * 256 + threadIdx.x) * 4;
  const float* src;
  unsigned short* dst;
  long off;
  if (i4 < 8388608) {
    src = x; dst = xb; off = i4;
  } else {
    long j = i4 - 8388608;
    int seg = (int)(j >> 22);
    off = j & 4194303;
    src = (seg == 0) ? wq : (seg == 1) ? wk : (seg == 2) ? wv : wo;
    dst = wb + ((long)seg << 22);
  }
  float4 v = *(const float4*)(src + off);
  ushort4 u;
  u.x = f2bf(v.x); u.y = f2bf(v.y); u.z = f2bf(v.z); u.w = f2bf(v.w);
  *(ushort4*)(dst + off) = u;
}

// ---------------- GEMM, m97 structure: 128x128 tile, BK=32, 4 waves -----------
// A [M][2048] bf16 row-major, W [N][2048] bf16 row-major (B^T form).
// MODE 0: fused QKV (N=6144): seg 0 -> Q[B,H,S,Dh] (scaled 1/sqrt(128)),
//         seg 1 -> K[B,H,S,Dh], seg 2 -> V^T[B,H,Dh,S].
// MODE 1: final projection, output FLOAT32 [M][2048] to d_out (+ bias b0).
template <int MODE>
__global__ __launch_bounds__(256, 2) void gemm_bt(
    const unsigned short* __restrict__ A, const unsigned short* __restrict__ W,
    const float* __restrict__ b0, const float* __restrict__ b1,
    const float* __restrict__ b2, unsigned short* __restrict__ oq,
    unsigned short* __restrict__ ok, unsigned short* __restrict__ ov,
    float* __restrict__ of) {
  __shared__ unsigned short lA[128 * 32];
  __shared__ unsigned short lB[128 * 32];
  const int t = threadIdx.x;
  const int lane = t & 63, wid = t >> 6;
  const int m0 = blockIdx.y * 128, n0 = blockIdx.x * 128;
  const int srow = t >> 2, scol = (t & 3) * 8;
  const unsigned short* ga = A + (long)(m0 + srow) * KK + scol;
  const unsigned short* gw = W + (long)(n0 + srow) * KK + scol;
  const int i16 = lane & 15, g4 = lane >> 4;
  const int wr = wid >> 1, wc = wid & 1;
  f32x4 acc[4][4] = {};
  for (int k0 = 0; k0 < KK; k0 += 32) {
    async16(ga + k0, &lA[wid * 512]);
    async16(ga + 64 * KK + k0, &lA[2048 + wid * 512]);
    async16(gw + k0, &lB[wid * 512]);
    async16(gw + 64 * KK + k0, &lB[2048 + wid * 512]);
    __syncthreads();
    bf16x8 af[4], bfr[4];
#pragma unroll
    for (int i = 0; i < 4; i++)
      af[i] = *(const bf16x8*)&lA[(wr * 64 + i * 16 + i16) * 32 + g4 * 8];
#pragma unroll
    for (int j = 0; j < 4; j++)
      bfr[j] = *(const bf16x8*)&lB[(wc * 64 + j * 16 + i16) * 32 + g4 * 8];
#pragma unroll
    for (int i = 0; i < 4; i++)
#pragma unroll
      for (int j = 0; j < 4; j++) acc[i][j] = mfma16(af[i], bfr[j], acc[i][j]);
    __syncthreads();
  }
#pragma unroll
  for (int i = 0; i < 4; i++) {
#pragma unroll
    for (int j = 0; j < 4; j++) {
      const int ng = n0 + wc * 64 + j * 16 + i16;
#pragma unroll
      for (int r = 0; r < 4; r++) {
        const int mg = m0 + wr * 64 + i * 16 + g4 * 4 + r;
        float v = acc[i][j][r];
        if (MODE == 1) {
          v += b0[ng];
          of[(long)mg * D_MODEL + ng] = v;  // fp32 output (ref dtype)
        } else {
          const int seg = ng >> 11, n = ng & 2047;
          const int h = n >> 7, d = n & 127;
          const int b_ = mg >> 11, s_ = mg & 2047;
          const long bh = b_ * NHEAD + h;
          if (seg == 0) {
            v = (v + b0[n]) * 0.08838834764831845f;  // 1/sqrt(128)
            oq[(bh * SS + s_) * DH + d] = f2bf(v);
          } else if (seg == 1) {
            v += b1[n];
            ok[(bh * SS + s_) * DH + d] = f2bf(v);
          } else {
            v += b2[n];
            ov[(bh * DH + d) * SS + s_] = f2bf(v);
          }
        }
      }
    }
  }
}

// ---------------- flash attention: 1 block = (b,h) x 64 q-rows, 4 waves -------
__global__ __launch_bounds__(256, 2) void attn_fwd(
    const unsigned short* __restrict__ Q, const unsigned short* __restrict__ Kb,
    const unsigned short* __restrict__ Vt, unsigned short* __restrict__ Ob) {
  __shared__ unsigned short lK[64 * 128];   // [64 kv rows][256B], XOR-swizzled
  __shared__ unsigned short lV[128 * 64];   // [128 d rows][128B], XOR-swizzled
  __shared__ unsigned short lP[4][16 * 64]; // per-wave P, [16 q][128B], swizzled
  const int t = threadIdx.x, lane = t & 63, wid = t >> 6;
  const int i16 = lane & 15, g4 = lane >> 4;
  const int qt = blockIdx.x, bh = blockIdx.y;
  const long qrow = (long)bh * SS + qt * 64 + wid * 16 + i16;
  bf16x8 qa[4];
#pragma unroll
  for (int ks = 0; ks < 4; ks++)
    qa[ks] = *(const bf16x8*)&Q[qrow * DH + ks * 32 + g4 * 8];
  f32x4 o[8] = {};
  float mrow[4] = {-1e30f, -1e30f, -1e30f, -1e30f};
  float lrow[4] = {0.f, 0.f, 0.f, 0.f};
  const char* kbase = (const char*)(Kb + (long)bh * SS * DH);
  const char* vbase = (const char*)(Vt + (long)bh * DH * SS);
  for (int kv0 = 0; kv0 < SS; kv0 += 64) {
    // ---- reg-stage K tile [64][128] and V^T tile [128][64] ----
    bf16x8 kreg[4], vreg[4];
#pragma unroll
    for (int r = 0; r < 4; r++) {
      const int idx = r * 4096 + t * 16;  // logical byte offset in tile
      kreg[r] = *(const bf16x8*)(kbase + (long)kv0 * 256 + idx);
      const int vrow = idx >> 7, vcol = idx & 127;
      vreg[r] = *(const bf16x8*)(vbase + (long)vrow * (SS * 2) + kv0 * 2 + vcol);
    }
#pragma unroll
    for (int r = 0; r < 4; r++) {
      const int idx = r * 4096 + t * 16;
      const int krow = idx >> 8, kcol = idx & 255;
      *(bf16x8*)((char*)lK + krow * 256 + (kcol ^ ((krow & 7) << 4))) = kreg[r];
      const int vrow = idx >> 7, vcol = idx & 127;
      *(bf16x8*)((char*)lV + vrow * 128 + (vcol ^ ((vrow & 7) << 4))) = vreg[r];
    }
    __syncthreads();
    // ---- QK^T: S tile 16x64 per wave ----
    f32x4 s4[4] = {};
#pragma unroll
    for (int kc = 0; kc < 4; kc++) {
      const int row = kc * 16 + i16;
#pragma unroll
      for (int ks = 0; ks < 4; ks++) {
        const int lb = row * 256 + ((ks * 64 + g4 * 16) ^ ((row & 7) << 4));
        bf16x8 kf = *(const bf16x8*)((const char*)lK + lb);
        s4[kc] = mfma16(qa[ks], kf, s4[kc]);
      }
    }
    // ---- online softmax (C-layout: col=lane&15, row=g4*4+r) ----
    float fac[4];
#pragma unroll
    for (int r = 0; r < 4; r++) {
      float mx = fmaxf(fmaxf(s4[0][r], s4[1][r]), fmaxf(s4[2][r], s4[3][r]));
      mx = fmaxf(mx, __shfl_xor(mx, 1));
      mx = fmaxf(mx, __shfl_xor(mx, 2));
      mx = fmaxf(mx, __shfl_xor(mx, 4));
      mx = fmaxf(mx, __shfl_xor(mx, 8));
      const float mnew = fmaxf(mrow[r], mx);
      fac[r] = __expf(mrow[r] - mnew);
      mrow[r] = mnew;
#pragma unroll
      for (int kc = 0; kc < 4; kc++) s4[kc][r] = __expf(s4[kc][r] - mnew);
      float su = s4[0][r] + s4[1][r] + s4[2][r] + s4[3][r];
      su += __shfl_xor(su, 1);
      su += __shfl_xor(su, 2);
      su += __shfl_xor(su, 4);
      su += __shfl_xor(su, 8);
      lrow[r] = lrow[r] * fac[r] + su;
    }
    // ---- P -> per-wave LDS (swizzled) to re-layout into A-fragments ----
#pragma unroll
    for (int r = 0; r < 4; r++) {
      const int prow = g4 * 4 + r;
      const int swz = (prow & 7) << 4;
#pragma unroll
      for (int kc = 0; kc < 4; kc++) {
        const int col = kc * 16 + i16;
        *(unsigned short*)((char*)&lP[wid][0] + prow * 128 + ((col * 2) ^ swz)) =
            f2bf(s4[kc][r]);
      }
    }
    // ---- rescale O ----
#pragma unroll
    for (int df = 0; df < 8; df++)
#pragma unroll
      for (int r = 0; r < 4; r++) o[df][r] *= fac[r];
    bf16x8 pa[2];
#pragma unroll
    for (int ks = 0; ks < 2; ks++) {
      const int lb = i16 * 128 + ((ks * 64 + g4 * 16) ^ ((i16 & 7) << 4));
      pa[ks] = *(const bf16x8*)((const char*)&lP[wid][0] + lb);
    }
    // ---- PV: O += P @ V (B-frag from V^T tile) ----
#pragma unroll
    for (int df = 0; df < 8; df++) {
#pragma unroll
      for (int ks = 0; ks < 2; ks++) {
        const int row = df * 16 + i16;
        const int lb = row * 128 + ((ks * 64 + g4 * 16) ^ ((row & 7) << 4));
        bf16x8 vf = *(const bf16x8*)((const char*)lV + lb);
        o[df] = mfma16(pa[ks], vf, o[df]);
      }
    }
    __syncthreads();
  }
  const int b_ = bh >> 4, h = bh & 15;
#pragma unroll
  for (int df = 0; df < 8; df++) {
#pragma unroll
    for (int r = 0; r < 4; r++) {
      const float v = o[df][r] / lrow[r];
      const long mg = (long)b_ * SS + qt * 64 + wid * 16 + g4 * 4 + r;
      Ob[mg * D_MODEL + h * DH + df * 16 + i16] = f2bf(v);
    }
  }
}

extern "C" void kernel_launch(void* const* d_in, const int* in_sizes, int n_in,
                              void* d_out, int out_size, void* d_ws,
                              size_t ws_size, hipStream_t stream) {
  const float* x = (const float*)d_in[0];
  const float* wq = (const float*)d_in[1];
  const float* bq = (const float*)d_in[2];
  const float* wk = (const float*)d_in[3];
  const float* bk = (const float*)d_in[4];
  const float* wv = (const float*)d_in[5];
  const float* bv = (const float*)d_in[6];
  const float* wo = (const float*)d_in[7];
  const float* bo = (const float*)d_in[8];
  char* ws = (char*)d_ws;
  // ws layout (bytes): xb 0..16M (later reused as Atb) | w bf16 16M..48M
  //                    | Q 48M | K 64M | V^T 80M..96M
  unsigned short* xb = (unsigned short*)(ws);
  unsigned short* wb = (unsigned short*)(ws + (16l << 20));
  unsigned short* wob = (unsigned short*)(ws + (40l << 20));
  unsigned short* Qb = (unsigned short*)(ws + (48l << 20));
  unsigned short* Kbf = (unsigned short*)(ws + (64l << 20));
  unsigned short* Vtb = (unsigned short*)(ws + (80l << 20));
  unsigned short* Atb = (unsigned short*)(ws);  // reuse xb region (dead by then)

  cast_all<<<24576, 256, 0, stream>>>(x, wq, wk, wv, wo, xb, wb);
  gemm_bt<0><<<dim3(48, 32), 256, 0, stream>>>(xb, wb, bq, bk, bv, Qb, Kbf,
                                               Vtb, nullptr);
  attn_fwd<<<dim3(32, 32), 256, 0, stream>>>(Qb, Kbf, Vtb, Atb);
  gemm_bt<1><<<dim3(16, 32), 256, 0, stream>>>(
      Atb, wob, bo, nullptr, nullptr, nullptr, nullptr, nullptr,
      (float*)d_out);
}

// Round 8
// 470.385 us; speedup vs baseline: 1.1128x; 1.1128x over previous
//
#include <hip/hip_runtime.h>

#define DEV __device__ __forceinline__

typedef __attribute__((ext_vector_type(8))) short bf16x8;
typedef __attribute__((ext_vector_type(4))) float f32x4;

constexpr int D_MODEL = 2048;
constexpr int NHEAD = 16;
constexpr int DH = 128;
constexpr int SS = 2048;   // sequence length
constexpr int KK = 2048;   // GEMM K dim

DEV unsigned short f2bf(float f) {
  unsigned int u = __builtin_bit_cast(unsigned int, f);
  u = (u + 0x7fff + ((u >> 16) & 1)) >> 16;  // RNE
  return (unsigned short)u;
}

DEV void async16(const void* g, void* l) {
  __builtin_amdgcn_global_load_lds(
      (const __attribute__((address_space(1))) unsigned int*)g,
      (__attribute__((address_space(3))) unsigned int*)l, 16, 0, 0);
}

DEV f32x4 mfma16(bf16x8 a, bf16x8 b, f32x4 c) {
  return __builtin_amdgcn_mfma_f32_16x16x32_bf16(a, b, c, 0, 0, 0);
}

// ---------------- cast fp32 -> bf16: x (8.4M) + wq,wk,wv,wo (4x4.19M) ----------
__global__ __launch_bounds__(256) void cast_all(
    const float* __restrict__ x, const float* __restrict__ wq,
    const float* __restrict__ wk, const float* __restrict__ wv,
    const float* __restrict__ wo, unsigned short* __restrict__ xb,
    unsigned short* __restrict__ wb) {
  long i4 = ((long)blockIdx.x * 256 + threadIdx.x) * 4;
  const float* src;
  unsigned short* dst;
  long off;
  if (i4 < 8388608) {
    src = x; dst = xb; off = i4;
  } else {
    long j = i4 - 8388608;
    int seg = (int)(j >> 22);
    off = j & 4194303;
    src = (seg == 0) ? wq : (seg == 1) ? wk : (seg == 2) ? wv : wo;
    dst = wb + ((long)seg << 22);
  }
  float4 v = *(const float4*)(src + off);
  ushort4 u;
  u.x = f2bf(v.x); u.y = f2bf(v.y); u.z = f2bf(v.z); u.w = f2bf(v.w);
  *(ushort4*)(dst + off) = u;
}

// ---------------- GEMM, m97 structure: 128x128 tile, BK=32, 4 waves -----------
// A [M][2048] bf16 row-major, W [N][2048] bf16 row-major (B^T form).
// MODE 0: fused QKV (N=6144): seg 0 -> Q[B,H,S,Dh] (scaled 1/sqrt(128)),
//         seg 1 -> K[B,H,S,Dh], seg 2 -> V^T[B,H,Dh,S].
// MODE 1: final projection, output FLOAT32 [M][2048] to d_out (+ bias b0).
template <int MODE>
__global__ __launch_bounds__(256, 2) void gemm_bt(
    const unsigned short* __restrict__ A, const unsigned short* __restrict__ W,
    const float* __restrict__ b0, const float* __restrict__ b1,
    const float* __restrict__ b2, unsigned short* __restrict__ oq,
    unsigned short* __restrict__ ok, unsigned short* __restrict__ ov,
    float* __restrict__ of) {
  __shared__ unsigned short lA[128 * 32];
  __shared__ unsigned short lB[128 * 32];
  const int t = threadIdx.x;
  const int lane = t & 63, wid = t >> 6;
  const int m0 = blockIdx.y * 128, n0 = blockIdx.x * 128;
  const int srow = t >> 2, scol = (t & 3) * 8;
  const unsigned short* ga = A + (long)(m0 + srow) * KK + scol;
  const unsigned short* gw = W + (long)(n0 + srow) * KK + scol;
  const int i16 = lane & 15, g4 = lane >> 4;
  const int wr = wid >> 1, wc = wid & 1;
  f32x4 acc[4][4] = {};
  for (int k0 = 0; k0 < KK; k0 += 32) {
    async16(ga + k0, &lA[wid * 512]);
    async16(ga + 64 * KK + k0, &lA[2048 + wid * 512]);
    async16(gw + k0, &lB[wid * 512]);
    async16(gw + 64 * KK + k0, &lB[2048 + wid * 512]);
    __syncthreads();
    bf16x8 af[4], bfr[4];
#pragma unroll
    for (int i = 0; i < 4; i++)
      af[i] = *(const bf16x8*)&lA[(wr * 64 + i * 16 + i16) * 32 + g4 * 8];
#pragma unroll
    for (int j = 0; j < 4; j++)
      bfr[j] = *(const bf16x8*)&lB[(wc * 64 + j * 16 + i16) * 32 + g4 * 8];
#pragma unroll
    for (int i = 0; i < 4; i++)
#pragma unroll
      for (int j = 0; j < 4; j++) acc[i][j] = mfma16(af[i], bfr[j], acc[i][j]);
    __syncthreads();
  }
#pragma unroll
  for (int i = 0; i < 4; i++) {
#pragma unroll
    for (int j = 0; j < 4; j++) {
      const int ng = n0 + wc * 64 + j * 16 + i16;
#pragma unroll
      for (int r = 0; r < 4; r++) {
        const int mg = m0 + wr * 64 + i * 16 + g4 * 4 + r;
        float v = acc[i][j][r];
        if (MODE == 1) {
          v += b0[ng];
          of[(long)mg * D_MODEL + ng] = v;  // fp32 output (ref dtype)
        } else {
          const int seg = ng >> 11, n = ng & 2047;
          const int h = n >> 7, d = n & 127;
          const int b_ = mg >> 11, s_ = mg & 2047;
          const long bh = b_ * NHEAD + h;
          if (seg == 0) {
            v = (v + b0[n]) * 0.08838834764831845f;  // 1/sqrt(128)
            oq[(bh * SS + s_) * DH + d] = f2bf(v);
          } else if (seg == 1) {
            v += b1[n];
            ok[(bh * SS + s_) * DH + d] = f2bf(v);
          } else {
            v += b2[n];
            ov[(bh * DH + d) * SS + s_] = f2bf(v);
          }
        }
      }
    }
  }
}

// ---------------- flash attention v2: 128 q-rows/block, 32 q-rows/wave --------
// Double-buffered K/V via global_load_lds (linear dest, inverse-swizzled
// source — correctness proven by round1==round2 output equivalence).
// 2-phase pipeline: issue next-tile loads, compute current, vmcnt(0)+barrier.
__global__ __launch_bounds__(256, 2) void attn_fwd(
    const unsigned short* __restrict__ Q, const unsigned short* __restrict__ Kb,
    const unsigned short* __restrict__ Vt, unsigned short* __restrict__ Ob) {
  __shared__ unsigned short lK[2][64 * 128];  // [buf][64 kv rows][256B] swz
  __shared__ unsigned short lV[2][128 * 64];  // [buf][128 d rows][128B] swz
  __shared__ unsigned short lP[4][16 * 64];   // per-wave P (reused per qi)
  const int t = threadIdx.x, lane = t & 63, wid = t >> 6;
  const int i16 = lane & 15, g4 = lane >> 4;
  const int qt = blockIdx.x, bh = blockIdx.y;
  bf16x8 qa[2][4];
#pragma unroll
  for (int qi = 0; qi < 2; qi++) {
    const long qrow = (long)bh * SS + qt * 128 + wid * 32 + qi * 16 + i16;
#pragma unroll
    for (int ks = 0; ks < 4; ks++)
      qa[qi][ks] = *(const bf16x8*)&Q[qrow * DH + ks * 32 + g4 * 8];
  }
  f32x4 o[2][8] = {};
  float mrow[2][4] = {{-1e30f, -1e30f, -1e30f, -1e30f},
                      {-1e30f, -1e30f, -1e30f, -1e30f}};
  float lrow[2][4] = {};
  const char* kbase = (const char*)(Kb + (long)bh * SS * DH);
  const char* vbase = (const char*)(Vt + (long)bh * DH * SS);

  auto STAGE = [&](int buf, int kv0) {
#pragma unroll
    for (int r = 0; r < 4; r++) {
      const int o_ = r * 4096 + t * 16;  // linear byte offset in tile
      // K: [64][256B] rows, swizzle f(byte)=byte^((row&7)<<4); src pre-inv-swz
      const int okk = o_ ^ (((o_ >> 8) & 7) << 4);
      async16(kbase + (long)kv0 * 256 + okk,
              (char*)lK + buf * 16384 + r * 4096 + wid * 1024);
      // V^T: [128][128B] rows
      const int vrow = o_ >> 7;
      const int inr = (o_ ^ ((vrow & 7) << 4)) & 127;
      async16(vbase + (long)vrow * (SS * 2) + kv0 * 2 + inr,
              (char*)lV + buf * 16384 + r * 4096 + wid * 1024);
    }
  };

  STAGE(0, 0);
  asm volatile("s_waitcnt vmcnt(0)");
  __syncthreads();
  int cur = 0;
  for (int it = 0; it < SS / 64; ++it) {
    if (it + 1 < SS / 64) STAGE(cur ^ 1, (it + 1) * 64);  // prefetch next tile
    const char* kb = (const char*)lK + cur * 16384;
    const char* vb = (const char*)lV + cur * 16384;
    // ---- QK^T: each wave 32 q-rows x 64 kv; kf read once, 2 MFMAs ----
    f32x4 s4[2][4] = {};
    __builtin_amdgcn_s_setprio(1);
#pragma unroll
    for (int kc = 0; kc < 4; kc++) {
      const int row = kc * 16 + i16;
#pragma unroll
      for (int ks = 0; ks < 4; ks++) {
        const int lb = row * 256 + ((ks * 64 + g4 * 16) ^ ((row & 7) << 4));
        bf16x8 kf = *(const bf16x8*)(kb + lb);
        s4[0][kc] = mfma16(qa[0][ks], kf, s4[0][kc]);
        s4[1][kc] = mfma16(qa[1][ks], kf, s4[1][kc]);
      }
    }
    __builtin_amdgcn_s_setprio(0);
    // ---- online softmax (C-layout: col=lane&15, row=g4*4+r) ----
    float fac[2][4];
#pragma unroll
    for (int qi = 0; qi < 2; qi++) {
#pragma unroll
      for (int r = 0; r < 4; r++) {
        float mx = fmaxf(fmaxf(s4[qi][0][r], s4[qi][1][r]),
                         fmaxf(s4[qi][2][r], s4[qi][3][r]));
        mx = fmaxf(mx, __shfl_xor(mx, 1));
        mx = fmaxf(mx, __shfl_xor(mx, 2));
        mx = fmaxf(mx, __shfl_xor(mx, 4));
        mx = fmaxf(mx, __shfl_xor(mx, 8));
        const float mnew = fmaxf(mrow[qi][r], mx);
        fac[qi][r] = __expf(mrow[qi][r] - mnew);
        mrow[qi][r] = mnew;
#pragma unroll
        for (int kc = 0; kc < 4; kc++)
          s4[qi][kc][r] = __expf(s4[qi][kc][r] - mnew);
        float su = s4[qi][0][r] + s4[qi][1][r] + s4[qi][2][r] + s4[qi][3][r];
        su += __shfl_xor(su, 1);
        su += __shfl_xor(su, 2);
        su += __shfl_xor(su, 4);
        su += __shfl_xor(su, 8);
        lrow[qi][r] = lrow[qi][r] * fac[qi][r] + su;
      }
    }
    // ---- P -> per-wave LDS (swizzled), re-layout into A-frags; reuse per qi --
    bf16x8 pa[2][2];
#pragma unroll
    for (int qi = 0; qi < 2; qi++) {
#pragma unroll
      for (int r = 0; r < 4; r++) {
        const int prow = g4 * 4 + r;
        const int swz = (prow & 7) << 4;
#pragma unroll
        for (int kc = 0; kc < 4; kc++) {
          const int col = kc * 16 + i16;
          *(unsigned short*)((char*)&lP[wid][0] + prow * 128 +
                             ((col * 2) ^ swz)) = f2bf(s4[qi][kc][r]);
        }
      }
#pragma unroll
      for (int ks = 0; ks < 2; ks++) {
        const int lb = i16 * 128 + ((ks * 64 + g4 * 16) ^ ((i16 & 7) << 4));
        pa[qi][ks] = *(const bf16x8*)((const char*)&lP[wid][0] + lb);
      }
    }
    // ---- rescale O ----
#pragma unroll
    for (int qi = 0; qi < 2; qi++)
#pragma unroll
      for (int df = 0; df < 8; df++)
#pragma unroll
        for (int r = 0; r < 4; r++) o[qi][df][r] *= fac[qi][r];
    // ---- PV: O += P @ V; vf read once, 2 MFMAs ----
    __builtin_amdgcn_s_setprio(1);
#pragma unroll
    for (int df = 0; df < 8; df++) {
#pragma unroll
      for (int ks = 0; ks < 2; ks++) {
        const int row = df * 16 + i16;
        const int lb = row * 128 + ((ks * 64 + g4 * 16) ^ ((row & 7) << 4));
        bf16x8 vf = *(const bf16x8*)(vb + lb);
        o[0][df] = mfma16(pa[0][ks], vf, o[0][df]);
        o[1][df] = mfma16(pa[1][ks], vf, o[1][df]);
      }
    }
    __builtin_amdgcn_s_setprio(0);
    asm volatile("s_waitcnt vmcnt(0)");
    __syncthreads();
    cur ^= 1;
  }
  const int b_ = bh >> 4, h = bh & 15;
#pragma unroll
  for (int qi = 0; qi < 2; qi++) {
#pragma unroll
    for (int df = 0; df < 8; df++) {
#pragma unroll
      for (int r = 0; r < 4; r++) {
        const float v = o[qi][df][r] / lrow[qi][r];
        const long mg =
            (long)b_ * SS + qt * 128 + wid * 32 + qi * 16 + g4 * 4 + r;
        Ob[mg * D_MODEL + h * DH + df * 16 + i16] = f2bf(v);
      }
    }
  }
}

extern "C" void kernel_launch(void* const* d_in, const int* in_sizes, int n_in,
                              void* d_out, int out_size, void* d_ws,
                              size_t ws_size, hipStream_t stream) {
  const float* x = (const float*)d_in[0];
  const float* wq = (const float*)d_in[1];
  const float* bq = (const float*)d_in[2];
  const float* wk = (const float*)d_in[3];
  const float* bk = (const float*)d_in[4];
  const float* wv = (const float*)d_in[5];
  const float* bv = (const float*)d_in[6];
  const float* wo = (const float*)d_in[7];
  const float* bo = (const float*)d_in[8];
  char* ws = (char*)d_ws;
  // ws layout (bytes): xb 0..16M (later reused as Atb) | w bf16 16M..48M
  //                    | Q 48M | K 64M | V^T 80M..96M
  unsigned short* xb = (unsigned short*)(ws);
  unsigned short* wb = (unsigned short*)(ws + (16l << 20));
  unsigned short* wob = (unsigned short*)(ws + (40l << 20));
  unsigned short* Qb = (unsigned short*)(ws + (48l << 20));
  unsigned short* Kbf = (unsigned short*)(ws + (64l << 20));
  unsigned short* Vtb = (unsigned short*)(ws + (80l << 20));
  unsigned short* Atb = (unsigned short*)(ws);  // reuse xb region (dead by then)

  cast_all<<<24576, 256, 0, stream>>>(x, wq, wk, wv, wo, xb, wb);
  gemm_bt<0><<<dim3(48, 32), 256, 0, stream>>>(xb, wb, bq, bk, bv, Qb, Kbf,
                                               Vtb, nullptr);
  attn_fwd<<<dim3(16, 32), 256, 0, stream>>>(Qb, Kbf, Vtb, Atb);
  gemm_bt<1><<<dim3(16, 32), 256, 0, stream>>>(
      Atb, wob, bo, nullptr, nullptr, nullptr, nullptr, nullptr,
      (float*)d_out);
}

// Round 9
// 456.784 us; speedup vs baseline: 1.1459x; 1.0298x over previous
//
#include <hip/hip_runtime.h>

#define DEV __device__ __forceinline__

typedef __attribute__((ext_vector_type(8))) short bf16x8;
typedef __attribute__((ext_vector_type(4))) float f32x4;

constexpr int D_MODEL = 2048;
constexpr int NHEAD = 16;
constexpr int DH = 128;
constexpr int SS = 2048;   // sequence length
constexpr int KK = 2048;   // GEMM K dim

DEV unsigned short f2bf(float f) {
  unsigned int u = __builtin_bit_cast(unsigned int, f);
  u = (u + 0x7fff + ((u >> 16) & 1)) >> 16;  // RNE
  return (unsigned short)u;
}

DEV void async16(const void* g, void* l) {
  __builtin_amdgcn_global_load_lds(
      (const __attribute__((address_space(1))) unsigned int*)g,
      (__attribute__((address_space(3))) unsigned int*)l, 16, 0, 0);
}

DEV f32x4 mfma16(bf16x8 a, bf16x8 b, f32x4 c) {
  return __builtin_amdgcn_mfma_f32_16x16x32_bf16(a, b, c, 0, 0, 0);
}

DEV float exp2f_raw(float x) {  // v_exp_f32 computes 2^x; reg-only asm is safe
  float y;
  asm("v_exp_f32 %0, %1" : "=v"(y) : "v"(x));
  return y;
}

// ---------------- cast fp32 -> bf16: x (8.4M) + wq,wk,wv,wo (4x4.19M) ----------
__global__ __launch_bounds__(256) void cast_all(
    const float* __restrict__ x, const float* __restrict__ wq,
    const float* __restrict__ wk, const float* __restrict__ wv,
    const float* __restrict__ wo, unsigned short* __restrict__ xb,
    unsigned short* __restrict__ wb) {
  long i4 = ((long)blockIdx.x * 256 + threadIdx.x) * 4;
  const float* src;
  unsigned short* dst;
  long off;
  if (i4 < 8388608) {
    src = x; dst = xb; off = i4;
  } else {
    long j = i4 - 8388608;
    int seg = (int)(j >> 22);
    off = j & 4194303;
    src = (seg == 0) ? wq : (seg == 1) ? wk : (seg == 2) ? wv : wo;
    dst = wb + ((long)seg << 22);
  }
  float4 v = *(const float4*)(src + off);
  ushort4 u;
  u.x = f2bf(v.x); u.y = f2bf(v.y); u.z = f2bf(v.z); u.w = f2bf(v.w);
  *(ushort4*)(dst + off) = u;
}

// ---------------- GEMM, m97 structure: 128x128 tile, BK=32, 4 waves -----------
// MODE 0: fused QKV (N=6144): seg 0 -> Q[B,H,S,Dh] (scaled log2e/sqrt(128)),
//         seg 1 -> K[B,H,S,Dh], seg 2 -> V^T[B,H,Dh,S].
// MODE 1: final projection, output FLOAT32 [M][2048] to d_out (+ bias b0).
template <int MODE>
__global__ __launch_bounds__(256, 2) void gemm_bt(
    const unsigned short* __restrict__ A, const unsigned short* __restrict__ W,
    const float* __restrict__ b0, const float* __restrict__ b1,
    const float* __restrict__ b2, unsigned short* __restrict__ oq,
    unsigned short* __restrict__ ok, unsigned short* __restrict__ ov,
    float* __restrict__ of) {
  __shared__ unsigned short lA[128 * 32];
  __shared__ unsigned short lB[128 * 32];
  const int t = threadIdx.x;
  const int lane = t & 63, wid = t >> 6;
  const int m0 = blockIdx.y * 128, n0 = blockIdx.x * 128;
  const int srow = t >> 2, scol = (t & 3) * 8;
  const unsigned short* ga = A + (long)(m0 + srow) * KK + scol;
  const unsigned short* gw = W + (long)(n0 + srow) * KK + scol;
  const int i16 = lane & 15, g4 = lane >> 4;
  const int wr = wid >> 1, wc = wid & 1;
  f32x4 acc[4][4] = {};
  for (int k0 = 0; k0 < KK; k0 += 32) {
    async16(ga + k0, &lA[wid * 512]);
    async16(ga + 64 * KK + k0, &lA[2048 + wid * 512]);
    async16(gw + k0, &lB[wid * 512]);
    async16(gw + 64 * KK + k0, &lB[2048 + wid * 512]);
    __syncthreads();
    bf16x8 af[4], bfr[4];
#pragma unroll
    for (int i = 0; i < 4; i++)
      af[i] = *(const bf16x8*)&lA[(wr * 64 + i * 16 + i16) * 32 + g4 * 8];
#pragma unroll
    for (int j = 0; j < 4; j++)
      bfr[j] = *(const bf16x8*)&lB[(wc * 64 + j * 16 + i16) * 32 + g4 * 8];
#pragma unroll
    for (int i = 0; i < 4; i++)
#pragma unroll
      for (int j = 0; j < 4; j++) acc[i][j] = mfma16(af[i], bfr[j], acc[i][j]);
    __syncthreads();
  }
#pragma unroll
  for (int i = 0; i < 4; i++) {
#pragma unroll
    for (int j = 0; j < 4; j++) {
      const int ng = n0 + wc * 64 + j * 16 + i16;
#pragma unroll
      for (int r = 0; r < 4; r++) {
        const int mg = m0 + wr * 64 + i * 16 + g4 * 4 + r;
        float v = acc[i][j][r];
        if (MODE == 1) {
          v += b0[ng];
          of[(long)mg * D_MODEL + ng] = v;  // fp32 output (ref dtype)
        } else {
          const int seg = ng >> 11, n = ng & 2047;
          const int h = n >> 7, d = n & 127;
          const int b_ = mg >> 11, s_ = mg & 2047;
          const long bh = b_ * NHEAD + h;
          if (seg == 0) {
            // scale = log2(e)/sqrt(128): softmax runs in exp2 domain
            v = (v + b0[n]) * (0.08838834764831845f * 1.4426950408889634f);
            oq[(bh * SS + s_) * DH + d] = f2bf(v);
          } else if (seg == 1) {
            v += b1[n];
            ok[(bh * SS + s_) * DH + d] = f2bf(v);
          } else {
            v += b2[n];
            ov[(bh * DH + d) * SS + s_] = f2bf(v);
          }
        }
      }
    }
  }
}

// ---------------- flash attention v3: 128 q-rows/block, 32 q-rows/wave --------
// v2 + (a) denominator via ones-column MFMA (no shuffle-sum), (b) exp2 domain
// (log2e folded into Q scale), (c) defer-max rescale THR=8, (d) rcp epilogue.
__global__ __launch_bounds__(256, 2) void attn_fwd(
    const unsigned short* __restrict__ Q, const unsigned short* __restrict__ Kb,
    const unsigned short* __restrict__ Vt, unsigned short* __restrict__ Ob) {
  __shared__ unsigned short lK[2][64 * 128];  // [buf][64 kv rows][256B] swz
  __shared__ unsigned short lV[2][128 * 64];  // [buf][128 d rows][128B] swz
  __shared__ unsigned short lP[4][16 * 64];   // per-wave P (reused per qi)
  const int t = threadIdx.x, lane = t & 63, wid = t >> 6;
  const int i16 = lane & 15, g4 = lane >> 4;
  const int qt = blockIdx.x, bh = blockIdx.y;
  bf16x8 qa[2][4];
#pragma unroll
  for (int qi = 0; qi < 2; qi++) {
    const long qrow = (long)bh * SS + qt * 128 + wid * 32 + qi * 16 + i16;
#pragma unroll
    for (int ks = 0; ks < 4; ks++)
      qa[qi][ks] = *(const bf16x8*)&Q[qrow * DH + ks * 32 + g4 * 8];
  }
  bf16x8 vones;
#pragma unroll
  for (int j = 0; j < 8; j++) vones[j] = (short)0x3F80;  // bf16 1.0
  f32x4 o[2][8] = {};
  f32x4 ol[2] = {};  // softmax denominators (ones-column accumulator)
  float mrow[2][4] = {{-1e30f, -1e30f, -1e30f, -1e30f},
                      {-1e30f, -1e30f, -1e30f, -1e30f}};
  const char* kbase = (const char*)(Kb + (long)bh * SS * DH);
  const char* vbase = (const char*)(Vt + (long)bh * DH * SS);

  auto STAGE = [&](int buf, int kv0) {
#pragma unroll
    for (int r = 0; r < 4; r++) {
      const int o_ = r * 4096 + t * 16;  // linear byte offset in tile
      const int okk = o_ ^ (((o_ >> 8) & 7) << 4);
      async16(kbase + (long)kv0 * 256 + okk,
              (char*)lK + buf * 16384 + r * 4096 + wid * 1024);
      const int vrow = o_ >> 7;
      const int inr = (o_ ^ ((vrow & 7) << 4)) & 127;
      async16(vbase + (long)vrow * (SS * 2) + kv0 * 2 + inr,
              (char*)lV + buf * 16384 + r * 4096 + wid * 1024);
    }
  };

  STAGE(0, 0);
  asm volatile("s_waitcnt vmcnt(0)");
  __syncthreads();
  int cur = 0;
  for (int it = 0; it < SS / 64; ++it) {
    if (it + 1 < SS / 64) STAGE(cur ^ 1, (it + 1) * 64);  // prefetch next tile
    const char* kb = (const char*)lK + cur * 16384;
    const char* vb = (const char*)lV + cur * 16384;
    // ---- QK^T (exp2-domain scores): 32 q-rows x 64 kv per wave ----
    f32x4 s4[2][4] = {};
    __builtin_amdgcn_s_setprio(1);
#pragma unroll
    for (int kc = 0; kc < 4; kc++) {
      const int row = kc * 16 + i16;
#pragma unroll
      for (int ks = 0; ks < 4; ks++) {
        const int lb = row * 256 + ((ks * 64 + g4 * 16) ^ ((row & 7) << 4));
        bf16x8 kf = *(const bf16x8*)(kb + lb);
        s4[0][kc] = mfma16(qa[0][ks], kf, s4[0][kc]);
        s4[1][kc] = mfma16(qa[1][ks], kf, s4[1][kc]);
      }
    }
    __builtin_amdgcn_s_setprio(0);
    // ---- online softmax, defer-max (C-layout: col=lane&15, row=g4*4+r) ----
#pragma unroll
    for (int qi = 0; qi < 2; qi++) {
      float mx[4];
#pragma unroll
      for (int r = 0; r < 4; r++) {
        float m_ = fmaxf(fmaxf(s4[qi][0][r], s4[qi][1][r]),
                         fmaxf(s4[qi][2][r], s4[qi][3][r]));
        m_ = fmaxf(m_, __shfl_xor(m_, 1));
        m_ = fmaxf(m_, __shfl_xor(m_, 2));
        m_ = fmaxf(m_, __shfl_xor(m_, 4));
        m_ = fmaxf(m_, __shfl_xor(m_, 8));
        mx[r] = m_;
      }
      const int ok = (mx[0] <= mrow[qi][0] + 8.f) &
                     (mx[1] <= mrow[qi][1] + 8.f) &
                     (mx[2] <= mrow[qi][2] + 8.f) &
                     (mx[3] <= mrow[qi][3] + 8.f);
      if (!__all(ok)) {  // rescale path (wave-uniform)
#pragma unroll
        for (int r = 0; r < 4; r++) {
          const float mnew = fmaxf(mrow[qi][r], mx[r]);
          const float fac = exp2f_raw(mrow[qi][r] - mnew);
          mrow[qi][r] = mnew;
          ol[qi][r] *= fac;
#pragma unroll
          for (int df = 0; df < 8; df++) o[qi][df][r] *= fac;
        }
      }
#pragma unroll
      for (int kc = 0; kc < 4; kc++)
#pragma unroll
        for (int r = 0; r < 4; r++)
          s4[qi][kc][r] = exp2f_raw(s4[qi][kc][r] - mrow[qi][r]);
    }
    // ---- P -> per-wave LDS (swizzled), re-layout into A-frags ----
    bf16x8 pa[2][2];
#pragma unroll
    for (int qi = 0; qi < 2; qi++) {
#pragma unroll
      for (int r = 0; r < 4; r++) {
        const int prow = g4 * 4 + r;
        const int swz = (prow & 7) << 4;
#pragma unroll
        for (int kc = 0; kc < 4; kc++) {
          const int col = kc * 16 + i16;
          *(unsigned short*)((char*)&lP[wid][0] + prow * 128 +
                             ((col * 2) ^ swz)) = f2bf(s4[qi][kc][r]);
        }
      }
#pragma unroll
      for (int ks = 0; ks < 2; ks++) {
        const int lb = i16 * 128 + ((ks * 64 + g4 * 16) ^ ((i16 & 7) << 4));
        pa[qi][ks] = *(const bf16x8*)((const char*)&lP[wid][0] + lb);
      }
    }
    // ---- PV: O += P @ V; denominators via ones-column MFMA ----
    __builtin_amdgcn_s_setprio(1);
#pragma unroll
    for (int ks = 0; ks < 2; ks++) {
      ol[0] = mfma16(pa[0][ks], vones, ol[0]);
      ol[1] = mfma16(pa[1][ks], vones, ol[1]);
    }
#pragma unroll
    for (int df = 0; df < 8; df++) {
#pragma unroll
      for (int ks = 0; ks < 2; ks++) {
        const int row = df * 16 + i16;
        const int lb = row * 128 + ((ks * 64 + g4 * 16) ^ ((row & 7) << 4));
        bf16x8 vf = *(const bf16x8*)(vb + lb);
        o[0][df] = mfma16(pa[0][ks], vf, o[0][df]);
        o[1][df] = mfma16(pa[1][ks], vf, o[1][df]);
      }
    }
    __builtin_amdgcn_s_setprio(0);
    asm volatile("s_waitcnt vmcnt(0)");
    __syncthreads();
    cur ^= 1;
  }
  const int b_ = bh >> 4, h = bh & 15;
#pragma unroll
  for (int qi = 0; qi < 2; qi++) {
    float inv[4];
#pragma unroll
    for (int r = 0; r < 4; r++) inv[r] = __builtin_amdgcn_rcpf(ol[qi][r]);
#pragma unroll
    for (int df = 0; df < 8; df++) {
#pragma unroll
      for (int r = 0; r < 4; r++) {
        const float v = o[qi][df][r] * inv[r];
        const long mg =
            (long)b_ * SS + qt * 128 + wid * 32 + qi * 16 + g4 * 4 + r;
        Ob[mg * D_MODEL + h * DH + df * 16 + i16] = f2bf(v);
      }
    }
  }
}

extern "C" void kernel_launch(void* const* d_in, const int* in_sizes, int n_in,
                              void* d_out, int out_size, void* d_ws,
                              size_t ws_size, hipStream_t stream) {
  const float* x = (const float*)d_in[0];
  const float* wq = (const float*)d_in[1];
  const float* bq = (const float*)d_in[2];
  const float* wk = (const float*)d_in[3];
  const float* bk = (const float*)d_in[4];
  const float* wv = (const float*)d_in[5];
  const float* bv = (const float*)d_in[6];
  const float* wo = (const float*)d_in[7];
  const float* bo = (const float*)d_in[8];
  char* ws = (char*)d_ws;
  unsigned short* xb = (unsigned short*)(ws);
  unsigned short* wb = (unsigned short*)(ws + (16l << 20));
  unsigned short* wob = (unsigned short*)(ws + (40l << 20));
  unsigned short* Qb = (unsigned short*)(ws + (48l << 20));
  unsigned short* Kbf = (unsigned short*)(ws + (64l << 20));
  unsigned short* Vtb = (unsigned short*)(ws + (80l << 20));
  unsigned short* Atb = (unsigned short*)(ws);  // reuse xb region (dead by then)

  cast_all<<<24576, 256, 0, stream>>>(x, wq, wk, wv, wo, xb, wb);
  gemm_bt<0><<<dim3(48, 32), 256, 0, stream>>>(xb, wb, bq, bk, bv, Qb, Kbf,
                                               Vtb, nullptr);
  attn_fwd<<<dim3(16, 32), 256, 0, stream>>>(Qb, Kbf, Vtb, Atb);
  gemm_bt<1><<<dim3(16, 32), 256, 0, stream>>>(
      Atb, wob, bo, nullptr, nullptr, nullptr, nullptr, nullptr,
      (float*)d_out);
}

// Round 10
// 425.716 us; speedup vs baseline: 1.2296x; 1.0730x over previous
//
#include <hip/hip_runtime.h>

#define DEV __device__ __forceinline__

typedef __attribute__((ext_vector_type(8))) short bf16x8;
typedef __attribute__((ext_vector_type(4))) float f32x4;

constexpr int D_MODEL = 2048;
constexpr int NHEAD = 16;
constexpr int DH = 128;
constexpr int SS = 2048;   // sequence length
constexpr int KK = 2048;   // GEMM K dim

DEV unsigned short f2bf(float f) {
  unsigned int u = __builtin_bit_cast(unsigned int, f);
  u = (u + 0x7fff + ((u >> 16) & 1)) >> 16;  // RNE
  return (unsigned short)u;
}

DEV void async16(const void* g, void* l) {
  __builtin_amdgcn_global_load_lds(
      (const __attribute__((address_space(1))) unsigned int*)g,
      (__attribute__((address_space(3))) unsigned int*)l, 16, 0, 0);
}

DEV f32x4 mfma16(bf16x8 a, bf16x8 b, f32x4 c) {
  return __builtin_amdgcn_mfma_f32_16x16x32_bf16(a, b, c, 0, 0, 0);
}

DEV float exp2f_raw(float x) {  // v_exp_f32 computes 2^x; reg-only asm is safe
  float y;
  asm("v_exp_f32 %0, %1" : "=v"(y) : "v"(x));
  return y;
}

// ---------------- cast fp32 -> bf16: x (8.4M) + wq,wk,wv,wo (4x4.19M) ----------
__global__ __launch_bounds__(256) void cast_all(
    const float* __restrict__ x, const float* __restrict__ wq,
    const float* __restrict__ wk, const float* __restrict__ wv,
    const float* __restrict__ wo, unsigned short* __restrict__ xb,
    unsigned short* __restrict__ wb) {
  long i4 = ((long)blockIdx.x * 256 + threadIdx.x) * 4;
  const float* src;
  unsigned short* dst;
  long off;
  if (i4 < 8388608) {
    src = x; dst = xb; off = i4;
  } else {
    long j = i4 - 8388608;
    int seg = (int)(j >> 22);
    off = j & 4194303;
    src = (seg == 0) ? wq : (seg == 1) ? wk : (seg == 2) ? wv : wo;
    dst = wb + ((long)seg << 22);
  }
  float4 v = *(const float4*)(src + off);
  ushort4 u;
  u.x = f2bf(v.x); u.y = f2bf(v.y); u.z = f2bf(v.z); u.w = f2bf(v.w);
  *(ushort4*)(dst + off) = u;
}

// ---------------- GEMM, m97 structure: 128x128 tile, BK=32, 4 waves -----------
// MODE 0: fused QKV (N=6144): seg 0 -> Q[B,H,S,Dh] (scaled log2e/sqrt(128)),
//         seg 1 -> K[B,H,S,Dh], seg 2 -> V^T[B,H,Dh,S].
//         Epilogue routes the 128x128 tile through LDS (V transposed at LDS-
//         write time) so ALL global stores are coalesced 16B/lane.
// MODE 1: final projection, output FLOAT32 [M][2048] to d_out (+ bias b0).
template <int MODE>
__global__ __launch_bounds__(256, 2) void gemm_bt(
    const unsigned short* __restrict__ A, const unsigned short* __restrict__ W,
    const float* __restrict__ b0, const float* __restrict__ b1,
    const float* __restrict__ b2, unsigned short* __restrict__ oq,
    unsigned short* __restrict__ ok, unsigned short* __restrict__ ov,
    float* __restrict__ of) {
  __shared__ unsigned short lA[128 * 32];
  __shared__ unsigned short lB[128 * 32];
  constexpr int LCS = (MODE == 0) ? 128 * 136 : 16;
  __shared__ __align__(16) unsigned short lC[LCS];  // pitch 136 de-conflicts
  const int t = threadIdx.x;
  const int lane = t & 63, wid = t >> 6;
  const int m0 = blockIdx.y * 128, n0 = blockIdx.x * 128;
  const int srow = t >> 2, scol = (t & 3) * 8;
  const unsigned short* ga = A + (long)(m0 + srow) * KK + scol;
  const unsigned short* gw = W + (long)(n0 + srow) * KK + scol;
  const int i16 = lane & 15, g4 = lane >> 4;
  const int wr = wid >> 1, wc = wid & 1;
  f32x4 acc[4][4] = {};
  for (int k0 = 0; k0 < KK; k0 += 32) {
    async16(ga + k0, &lA[wid * 512]);
    async16(ga + 64 * KK + k0, &lA[2048 + wid * 512]);
    async16(gw + k0, &lB[wid * 512]);
    async16(gw + 64 * KK + k0, &lB[2048 + wid * 512]);
    __syncthreads();
    bf16x8 af[4], bfr[4];
#pragma unroll
    for (int i = 0; i < 4; i++)
      af[i] = *(const bf16x8*)&lA[(wr * 64 + i * 16 + i16) * 32 + g4 * 8];
#pragma unroll
    for (int j = 0; j < 4; j++)
      bfr[j] = *(const bf16x8*)&lB[(wc * 64 + j * 16 + i16) * 32 + g4 * 8];
#pragma unroll
    for (int i = 0; i < 4; i++)
#pragma unroll
      for (int j = 0; j < 4; j++) acc[i][j] = mfma16(af[i], bfr[j], acc[i][j]);
    __syncthreads();
  }
  if (MODE == 1) {
#pragma unroll
    for (int i = 0; i < 4; i++) {
#pragma unroll
      for (int j = 0; j < 4; j++) {
        const int ng = n0 + wc * 64 + j * 16 + i16;
#pragma unroll
        for (int r = 0; r < 4; r++) {
          const int mg = m0 + wr * 64 + i * 16 + g4 * 4 + r;
          of[(long)mg * D_MODEL + ng] = acc[i][j][r] + b0[ng];
        }
      }
    }
  } else {
    const int seg = n0 >> 11;          // uniform per block (128 | 2048)
    const int h0 = (n0 & 2047) >> 7;   // block spans exactly one head
    const int b_ = m0 >> 11;           // block spans one batch
    const int s0_ = m0 & 2047;
#pragma unroll
    for (int i = 0; i < 4; i++) {
#pragma unroll
      for (int j = 0; j < 4; j++) {
        const int nl = wc * 64 + j * 16 + i16;
        const int n = (n0 & 2047) + nl;
#pragma unroll
        for (int r = 0; r < 4; r++) {
          const int ml = wr * 64 + i * 16 + g4 * 4 + r;
          float v = acc[i][j][r];
          if (seg == 0) {
            // scale = log2(e)/sqrt(128): softmax runs in exp2 domain
            v = (v + b0[n]) * (0.08838834764831845f * 1.4426950408889634f);
            lC[ml * 136 + nl] = f2bf(v);
          } else if (seg == 1) {
            lC[ml * 136 + nl] = f2bf(v + b1[n]);
          } else {  // V: store transposed so V^T rows read back contiguous
            lC[nl * 136 + ml] = f2bf(v + b2[n]);
          }
        }
      }
    }
    __syncthreads();
#pragma unroll
    for (int rep = 0; rep < 8; rep++) {
      const int idx = rep * 256 + t;
      const int row = idx >> 4, c16 = idx & 15;
      const bf16x8 v8 = *(const bf16x8*)&lC[row * 136 + c16 * 8];
      if (seg == 2) {
        // row = d, chunk covers s: V^T[b,h0,row, s0_+c16*8 ..]
        *(bf16x8*)&ov[((long)(b_ * NHEAD + h0) * DH + row) * SS + s0_ +
                      c16 * 8] = v8;
      } else {
        unsigned short* base = (seg == 0) ? oq : ok;
        // row = s, chunk covers d
        *(bf16x8*)&base[((long)(b_ * NHEAD + h0) * SS + (s0_ + row)) * DH +
                        c16 * 8] = v8;
      }
    }
  }
}

// ---------------- flash attention v4: 256 q-rows/block (8 waves, 512 thr) ----
// One K/V stage now serves 256 q-rows (staging traffic halved vs v3);
// LDS 80KB -> up to 2 blocks/CU (16 waves). Per-wave structure unchanged.
__global__ __launch_bounds__(512, 2) void attn_fwd(
    const unsigned short* __restrict__ Q, const unsigned short* __restrict__ Kb,
    const unsigned short* __restrict__ Vt, unsigned short* __restrict__ Ob) {
  __shared__ unsigned short lK[2][64 * 128];  // [buf][64 kv rows][256B] swz
  __shared__ unsigned short lV[2][128 * 64];  // [buf][128 d rows][128B] swz
  __shared__ unsigned short lP[8][16 * 64];   // per-wave P (reused per qi)
  const int t = threadIdx.x, lane = t & 63, wid = t >> 6;
  const int i16 = lane & 15, g4 = lane >> 4;
  const int qt = blockIdx.x, bh = blockIdx.y;
  bf16x8 qa[2][4];
#pragma unroll
  for (int qi = 0; qi < 2; qi++) {
    const long qrow = (long)bh * SS + qt * 256 + wid * 32 + qi * 16 + i16;
#pragma unroll
    for (int ks = 0; ks < 4; ks++)
      qa[qi][ks] = *(const bf16x8*)&Q[qrow * DH + ks * 32 + g4 * 8];
  }
  bf16x8 vones;
#pragma unroll
  for (int j = 0; j < 8; j++) vones[j] = (short)0x3F80;  // bf16 1.0
  f32x4 o[2][8] = {};
  f32x4 ol[2] = {};  // softmax denominators (ones-column accumulator)
  float mrow[2][4] = {{-1e30f, -1e30f, -1e30f, -1e30f},
                      {-1e30f, -1e30f, -1e30f, -1e30f}};
  const char* kbase = (const char*)(Kb + (long)bh * SS * DH);
  const char* vbase = (const char*)(Vt + (long)bh * DH * SS);

  auto STAGE = [&](int buf, int kv0) {
#pragma unroll
    for (int r = 0; r < 2; r++) {
      const int o_ = r * 8192 + t * 16;  // linear byte offset in 16KB tile
      const int okk = o_ ^ (((o_ >> 8) & 7) << 4);
      async16(kbase + (long)kv0 * 256 + okk,
              (char*)lK + buf * 16384 + r * 8192 + wid * 1024);
      const int vrow = o_ >> 7;
      const int inr = (o_ ^ ((vrow & 7) << 4)) & 127;
      async16(vbase + (long)vrow * (SS * 2) + kv0 * 2 + inr,
              (char*)lV + buf * 16384 + r * 8192 + wid * 1024);
    }
  };

  STAGE(0, 0);
  asm volatile("s_waitcnt vmcnt(0)");
  __syncthreads();
  int cur = 0;
  for (int it = 0; it < SS / 64; ++it) {
    if (it + 1 < SS / 64) STAGE(cur ^ 1, (it + 1) * 64);  // prefetch next tile
    const char* kb = (const char*)lK + cur * 16384;
    const char* vb = (const char*)lV + cur * 16384;
    // ---- QK^T (exp2-domain scores): 32 q-rows x 64 kv per wave ----
    f32x4 s4[2][4] = {};
    __builtin_amdgcn_s_setprio(1);
#pragma unroll
    for (int kc = 0; kc < 4; kc++) {
      const int row = kc * 16 + i16;
#pragma unroll
      for (int ks = 0; ks < 4; ks++) {
        const int lb = row * 256 + ((ks * 64 + g4 * 16) ^ ((row & 7) << 4));
        bf16x8 kf = *(const bf16x8*)(kb + lb);
        s4[0][kc] = mfma16(qa[0][ks], kf, s4[0][kc]);
        s4[1][kc] = mfma16(qa[1][ks], kf, s4[1][kc]);
      }
    }
    __builtin_amdgcn_s_setprio(0);
    // ---- online softmax, defer-max (C-layout: col=lane&15, row=g4*4+r) ----
#pragma unroll
    for (int qi = 0; qi < 2; qi++) {
      float mx[4];
#pragma unroll
      for (int r = 0; r < 4; r++) {
        float m_ = fmaxf(fmaxf(s4[qi][0][r], s4[qi][1][r]),
                         fmaxf(s4[qi][2][r], s4[qi][3][r]));
        m_ = fmaxf(m_, __shfl_xor(m_, 1));
        m_ = fmaxf(m_, __shfl_xor(m_, 2));
        m_ = fmaxf(m_, __shfl_xor(m_, 4));
        m_ = fmaxf(m_, __shfl_xor(m_, 8));
        mx[r] = m_;
      }
      const int ok = (mx[0] <= mrow[qi][0] + 8.f) &
                     (mx[1] <= mrow[qi][1] + 8.f) &
                     (mx[2] <= mrow[qi][2] + 8.f) &
                     (mx[3] <= mrow[qi][3] + 8.f);
      if (!__all(ok)) {  // rescale path (wave-uniform)
#pragma unroll
        for (int r = 0; r < 4; r++) {
          const float mnew = fmaxf(mrow[qi][r], mx[r]);
          const float fac = exp2f_raw(mrow[qi][r] - mnew);
          mrow[qi][r] = mnew;
          ol[qi][r] *= fac;
#pragma unroll
          for (int df = 0; df < 8; df++) o[qi][df][r] *= fac;
        }
      }
#pragma unroll
      for (int kc = 0; kc < 4; kc++)
#pragma unroll
        for (int r = 0; r < 4; r++)
          s4[qi][kc][r] = exp2f_raw(s4[qi][kc][r] - mrow[qi][r]);
    }
    // ---- P -> per-wave LDS (swizzled), re-layout into A-frags ----
    bf16x8 pa[2][2];
#pragma unroll
    for (int qi = 0; qi < 2; qi++) {
#pragma unroll
      for (int r = 0; r < 4; r++) {
        const int prow = g4 * 4 + r;
        const int swz = (prow & 7) << 4;
#pragma unroll
        for (int kc = 0; kc < 4; kc++) {
          const int col = kc * 16 + i16;
          *(unsigned short*)((char*)&lP[wid][0] + prow * 128 +
                             ((col * 2) ^ swz)) = f2bf(s4[qi][kc][r]);
        }
      }
#pragma unroll
      for (int ks = 0; ks < 2; ks++) {
        const int lb = i16 * 128 + ((ks * 64 + g4 * 16) ^ ((i16 & 7) << 4));
        pa[qi][ks] = *(const bf16x8*)((const char*)&lP[wid][0] + lb);
      }
    }
    // ---- PV: O += P @ V; denominators via ones-column MFMA ----
    __builtin_amdgcn_s_setprio(1);
#pragma unroll
    for (int ks = 0; ks < 2; ks++) {
      ol[0] = mfma16(pa[0][ks], vones, ol[0]);
      ol[1] = mfma16(pa[1][ks], vones, ol[1]);
    }
#pragma unroll
    for (int df = 0; df < 8; df++) {
#pragma unroll
      for (int ks = 0; ks < 2; ks++) {
        const int row = df * 16 + i16;
        const int lb = row * 128 + ((ks * 64 + g4 * 16) ^ ((row & 7) << 4));
        bf16x8 vf = *(const bf16x8*)(vb + lb);
        o[0][df] = mfma16(pa[0][ks], vf, o[0][df]);
        o[1][df] = mfma16(pa[1][ks], vf, o[1][df]);
      }
    }
    __builtin_amdgcn_s_setprio(0);
    asm volatile("s_waitcnt vmcnt(0)");
    __syncthreads();
    cur ^= 1;
  }
  const int b_ = bh >> 4, h = bh & 15;
#pragma unroll
  for (int qi = 0; qi < 2; qi++) {
    float inv[4];
#pragma unroll
    for (int r = 0; r < 4; r++) inv[r] = __builtin_amdgcn_rcpf(ol[qi][r]);
#pragma unroll
    for (int df = 0; df < 8; df++) {
#pragma unroll
      for (int r = 0; r < 4; r++) {
        const float v = o[qi][df][r] * inv[r];
        const long mg =
            (long)b_ * SS + qt * 256 + wid * 32 + qi * 16 + g4 * 4 + r;
        Ob[mg * D_MODEL + h * DH + df * 16 + i16] = f2bf(v);
      }
    }
  }
}

extern "C" void kernel_launch(void* const* d_in, const int* in_sizes, int n_in,
                              void* d_out, int out_size, void* d_ws,
                              size_t ws_size, hipStream_t stream) {
  const float* x = (const float*)d_in[0];
  const float* wq = (const float*)d_in[1];
  const float* bq = (const float*)d_in[2];
  const float* wk = (const float*)d_in[3];
  const float* bk = (const float*)d_in[4];
  const float* wv = (const float*)d_in[5];
  const float* bv = (const float*)d_in[6];
  const float* wo = (const float*)d_in[7];
  const float* bo = (const float*)d_in[8];
  char* ws = (char*)d_ws;
  unsigned short* xb = (unsigned short*)(ws);
  unsigned short* wb = (unsigned short*)(ws + (16l << 20));
  unsigned short* wob = (unsigned short*)(ws + (40l << 20));
  unsigned short* Qb = (unsigned short*)(ws + (48l << 20));
  unsigned short* Kbf = (unsigned short*)(ws + (64l << 20));
  unsigned short* Vtb = (unsigned short*)(ws + (80l << 20));
  unsigned short* Atb = (unsigned short*)(ws);  // reuse xb region (dead by then)

  cast_all<<<24576, 256, 0, stream>>>(x, wq, wk, wv, wo, xb, wb);
  gemm_bt<0><<<dim3(48, 32), 256, 0, stream>>>(xb, wb, bq, bk, bv, Qb, Kbf,
                                               Vtb, nullptr);
  attn_fwd<<<dim3(8, 32), 512, 0, stream>>>(Qb, Kbf, Vtb, Atb);
  gemm_bt<1><<<dim3(16, 32), 256, 0, stream>>>(
      Atb, wob, bo, nullptr, nullptr, nullptr, nullptr, nullptr,
      (float*)d_out);
}